// Round 12
// baseline (207.062 us; speedup 1.0000x reference)
//
#include <hip/hip_runtime.h>

#define OUT_F 11008
#define IN_F  4096
#define D     8                // weight prefetch depth (1KB chunks)

// R11: page-locality + queue-decoupling.
// Wave = 4 CONSECUTIVE rows x 4 batches, rows processed ONE AT A TIME ->
// the wave's weight traffic is a single contiguous 64KB sequential stream
// (DRAM-page friendly), with a rolling depth-8 register prefetch. The
// vmcnt queue carries ONLY weights: x is read from LDS (lgkmcnt), so the
// FMA's x-wait never retires in-flight weight loads.
// Block = 512 thr = 8 waves, one batch-half: x_lds = 4 rows x 4096 f32 =
// 64KB -> 2 blocks/CU = 16 waves/CU, ~8KB/wave in flight = 128KB/CU.
// Grid = 344 row-blocks x 2 batch-halves (bh = LOW bit: twin blocks that
// read the SAME weight rows dispatch adjacently -> L2/L3 temporal reuse).
// zero-point folded: out = s*(dot - zp*rowsum(x_b)) + bias.
// NOTE: plain __launch_bounds__ — ",N" variants forced spills (R3).
__global__ __launch_bounds__(512) void qlinear_kernel(
        const float* __restrict__ in, const int* __restrict__ qw,
        const int* __restrict__ zp, const float* __restrict__ scale,
        const float* __restrict__ bias, float* __restrict__ out) {
    const int lane = threadIdx.x & 63;
    const int wave = threadIdx.x >> 6;       // 0..7
    const int bh   = blockIdx.x & 1;         // batch half (low bit!)
    const int rblk = blockIdx.x >> 1;        // 0..343
    const int row0 = rblk * 32 + wave * 4;   // wave's 4 consecutive rows
    const int l4   = lane * 4;

    __shared__ float xs[4][IN_F];            // 64 KB: this half's 4 batch rows

    // ---- stage x: wave pair (b = wave>>1) stages batch row b, split by wave&1
    {
        const int b = wave >> 1;
        const int h = wave & 1;
        const float* src = in + (size_t)(bh * 4 + b) * IN_F + h * (IN_F / 2);
        float*       dst = &xs[b][h * (IN_F / 2)];
        #pragma unroll
        for (int i = 0; i < (IN_F / 2) / 256; ++i) {   // 8 x 1KB
            const int o = i * 256 + l4;
            *reinterpret_cast<float4*>(dst + o) =
                *reinterpret_cast<const float4*>(src + o);
        }
    }
    __syncthreads();   // the only barrier

    // ---- issue the first D weight chunks NOW; their latency hides under
    // the S-phase below (which is pure LDS/VALU -> no vmcnt interference).
    const int* qbase = qw + (size_t)row0 * IN_F + l4;  // wave's 64KB region
    int4 wbuf[D];
    #pragma unroll
    for (int p = 0; p < D; ++p)
        wbuf[p] = *reinterpret_cast<const int4*>(qbase + p * 256);

    // ---- rowsum S (per wave, redundant): ends with S_mine = S[lane&3]
    float asum[4] = {0.f, 0.f, 0.f, 0.f};
    #pragma unroll
    for (int j = 0; j < IN_F / 256; ++j) {
        #pragma unroll
        for (int b = 0; b < 4; ++b) {
            const float4 x = *reinterpret_cast<const float4*>(&xs[b][j * 256 + l4]);
            asum[b] += (x.x + x.y) + (x.z + x.w);
        }
    }
    float S_mine;
    {
        float v0 = asum[0], v1 = asum[1], v2 = asum[2], v3 = asum[3];
        {   const bool hi = lane & 1;
            float a0 = hi ? v1 : v0, s0 = hi ? v0 : v1;
            float a1 = hi ? v3 : v2, s1 = hi ? v2 : v3;
            v0 = a0 + __shfl_xor(s0, 1);
            v1 = a1 + __shfl_xor(s1, 1); }
        {   const bool hi = lane & 2;
            float a = hi ? v1 : v0, s = hi ? v0 : v1;
            v0 = a + __shfl_xor(s, 2); }
        v0 += __shfl_xor(v0, 4);
        v0 += __shfl_xor(v0, 8);
        v0 += __shfl_xor(v0, 16);
        v0 += __shfl_xor(v0, 32);
        S_mine = v0;                         // full rowsum of batch (lane&3)
    }

    // ---- main stream: 64 flat 1KB chunks = 4 rows x 16 steps, sequential
    float acc[4] = {0.f, 0.f, 0.f, 0.f};
    #pragma unroll
    for (int rr = 0; rr < 4; ++rr) {
        #pragma unroll
        for (int t = 0; t < 16; ++t) {
            const int fs = rr * 16 + t;
            // consume chunk fs (compiler waits vmcnt(D-1): retires fs only)
            const int4 wv = wbuf[fs & (D - 1)];
            const float f0 = (float)wv.x, f1 = (float)wv.y,
                        f2 = (float)wv.z, f3 = (float)wv.w;
            // refill the freed slot with chunk fs+D (sequential address)
            if (fs + D < 64)
                wbuf[fs & (D - 1)] =
                    *reinterpret_cast<const int4*>(qbase + (fs + D) * 256);
            // x from LDS (lgkmcnt; conflict-free consecutive-16B pattern)
            #pragma unroll
            for (int b = 0; b < 4; ++b) {
                const float4 x =
                    *reinterpret_cast<const float4*>(&xs[b][t * 256 + l4]);
                acc[b] += f0 * x.x + f1 * x.y + f2 * x.z + f3 * x.w;
            }
        }

        // ---- per-row epilogue: reduce acc[4] across lanes, write 4 outputs
        {
            const int row = row0 + rr;
            float v0 = acc[0], v1 = acc[1], v2 = acc[2], v3 = acc[3];
            {   const bool hi = lane & 1;
                float a0 = hi ? v1 : v0, s0 = hi ? v0 : v1;
                float a1 = hi ? v3 : v2, s1 = hi ? v2 : v3;
                v0 = a0 + __shfl_xor(s0, 1);
                v1 = a1 + __shfl_xor(s1, 1); }
            {   const bool hi = lane & 2;
                float a = hi ? v1 : v0, s = hi ? v0 : v1;
                v0 = a + __shfl_xor(s, 2); }
            v0 += __shfl_xor(v0, 4);
            v0 += __shfl_xor(v0, 8);
            v0 += __shfl_xor(v0, 16);
            v0 += __shfl_xor(v0, 32);        // lane holds dot(row, lane&3)
            if (lane < 4) {
                out[(size_t)(bh * 4 + lane) * OUT_F + row] =
                    scale[row] * (v0 - (float)zp[row] * S_mine) + bias[row];
            }
            acc[0] = acc[1] = acc[2] = acc[3] = 0.f;
        }
    }
}

extern "C" void kernel_launch(void* const* d_in, const int* in_sizes, int n_in,
                              void* d_out, int out_size, void* d_ws, size_t ws_size,
                              hipStream_t stream) {
    const float* in    = (const float*)d_in[0];
    const int*   qw    = (const int*)  d_in[1];
    const int*   zp    = (const int*)  d_in[2];
    const float* scale = (const float*)d_in[3];
    const float* bias  = (const float*)d_in[4];
    float*       out   = (float*)d_out;

    const int blocks = (OUT_F / 32) * 2;   // 344 row-blocks x 2 batch-halves
    qlinear_kernel<<<blocks, 512, 0, stream>>>(in, qw, zp, scale, bias, out);
}

// Round 13
// 87.056 us; speedup vs baseline: 2.3785x; 2.3785x over previous
//
#include <hip/hip_runtime.h>

#define OUT_F 11008
#define IN_F  4096
#define KHALF (IN_F / 2)       // K split across wave pairs
#define KSTEP 256              // k per step: lane*4, int4/float4 16B loads
#define NSTEP (KHALF / KSTEP)  // 8 steps

// R12 = R4 (best, 40.5us) + register diet: the 8 persistent asum registers
// are replaced by a PRE-PASS that re-reads the wave's x K-half (L2-hot,
// ~88MB aggregate extra L2 traffic) and reduces to ONE register S before
// the K-loop. Main-loop peak: acc 32 + x 32 + w-dbuf 32 + S 1 + temps
// ~ 115 < 128-VGPR cliff -> 3 waves/SIMD (R4 sat at 136 -> 2/SIMD).
// Everything else identical to R4: block = 4 waves = 2 groups x 2 K-halves;
// per step issue x(t) (8x float4, L2) then w(t+1) (4x int4, depth-1
// prefetch); FMA's x-wait (vmcnt(4)) retires w(t), keeps w(t+1) in flight.
// zero-point folded: out = s*(dot - zp*rowsum(x_b)) + bias.
// NOTE: plain __launch_bounds__ — ",N" variants forced spills (R3).
__global__ __launch_bounds__(256) void qlinear_kernel(
        const float* __restrict__ in, const int* __restrict__ qw,
        const int* __restrict__ zp, const float* __restrict__ scale,
        const float* __restrict__ bias, float* __restrict__ out) {
    const int lane  = threadIdx.x & 63;
    const int wave  = threadIdx.x >> 6;          // 0..3
    const int half  = wave & 1;                  // K-half
    const int group = blockIdx.x * 2 + (wave >> 1);
    const int row0  = group * 4;
    const int l4    = lane * 4;

    const int*   qp = qw + (size_t)row0 * IN_F + half * KHALF + l4;
    const float* xp = in + half * KHALF + l4;

    // ---- PRE-PASS: rowsum of this K-half, reduced to ONE register ----
    // asum[8] lives only here; dead before the K-loop -> no main-loop cost.
    float S;
    {
        float asum[8] = {0.f, 0.f, 0.f, 0.f, 0.f, 0.f, 0.f, 0.f};
        #pragma unroll
        for (int t = 0; t < NSTEP; ++t) {
            #pragma unroll
            for (int b = 0; b < 8; ++b) {
                const float4 x =
                    *reinterpret_cast<const float4*>(xp + b * IN_F + t * KSTEP);
                asum[b] += (x.x + x.y) + (x.z + x.w);
            }
        }
        // register-halving tree: 3 levels -> lane holds batch (lane&7);
        // then fold remaining lane bits.
        #pragma unroll
        for (int k = 0; k < 3; ++k) {
            const bool hi = (lane >> k) & 1;
            const int  nn = 8 >> k;
            #pragma unroll
            for (int i = 0; i < 8; ++i) {
                if (i < nn / 2) {
                    float keep = hi ? asum[2 * i + 1] : asum[2 * i];
                    float send = hi ? asum[2 * i]     : asum[2 * i + 1];
                    asum[i] = keep + __shfl_xor(send, 1 << k);
                }
            }
        }
        S = asum[0];
        S += __shfl_xor(S, 8);
        S += __shfl_xor(S, 16);
        S += __shfl_xor(S, 32);   // K-half rowsum of batch (lane&7)
    }

    // ---- main K-loop (R4 verbatim, minus asum) ----
    float acc[4][8];
    #pragma unroll
    for (int r = 0; r < 4; ++r)
        #pragma unroll
        for (int b = 0; b < 8; ++b) acc[r][b] = 0.f;

    int4 wbuf[2][4];
    #pragma unroll
    for (int r = 0; r < 4; ++r)
        wbuf[0][r] = *reinterpret_cast<const int4*>(qp + r * IN_F);

    #pragma unroll
    for (int t = 0; t < NSTEP; ++t) {
        const int c = t & 1, n = c ^ 1;

        // x(t): issued first so the FMA's wait on x (vmcnt(4)) retires w(t)
        // but keeps w(t+1) in flight.
        float4 x[8];
        #pragma unroll
        for (int b = 0; b < 8; ++b)
            x[b] = *reinterpret_cast<const float4*>(xp + b * IN_F + t * KSTEP);

        // w(t+1): depth-1 prefetch of the weight stream
        if (t + 1 < NSTEP) {
            #pragma unroll
            for (int r = 0; r < 4; ++r)
                wbuf[n][r] = *reinterpret_cast<const int4*>(qp + r * IN_F + (t + 1) * KSTEP);
        }

        float f[4][4];
        #pragma unroll
        for (int r = 0; r < 4; ++r) {
            f[r][0] = (float)wbuf[c][r].x;
            f[r][1] = (float)wbuf[c][r].y;
            f[r][2] = (float)wbuf[c][r].z;
            f[r][3] = (float)wbuf[c][r].w;
        }
        #pragma unroll
        for (int b = 0; b < 8; ++b) {
            const float4 xv = x[b];
            #pragma unroll
            for (int r = 0; r < 4; ++r)
                acc[r][b] += f[r][0] * xv.x + f[r][1] * xv.y
                           + f[r][2] * xv.z + f[r][3] * xv.w;
        }
    }

    // --- cross-lane reduce of 32 dot-accumulators (register-halving tree):
    // 5 levels -> lane l holds index (l&31) over its 32-lane half; +xor32
    // -> full 64-lane sum on lanes 0..31. index = r*8 + b.
    float v[32];
    #pragma unroll
    for (int r = 0; r < 4; ++r)
        #pragma unroll
        for (int b = 0; b < 8; ++b) v[r * 8 + b] = acc[r][b];

    #pragma unroll
    for (int k = 0; k < 5; ++k) {
        const bool hi = (lane >> k) & 1;
        const int  nn = 32 >> k;
        #pragma unroll
        for (int i = 0; i < 32; ++i) {
            if (i < nn / 2) {
                float keep = hi ? v[2 * i + 1] : v[2 * i];
                float send = hi ? v[2 * i]     : v[2 * i + 1];
                v[i] = keep + __shfl_xor(send, 1 << k);
            }
        }
    }
    const float total = v[0] + __shfl_xor(v[0], 32);   // this wave's K-half dot

    // --- combine the two K-halves of each group via LDS ---
    __shared__ float ldsv[4][32];
    __shared__ float ldsS[4][8];
    if (lane < 32) ldsv[wave][lane] = total;
    if (lane < 8)  ldsS[wave][lane] = S;     // lane holds batch lane (lane<8)
    __syncthreads();

    if (half == 0 && lane < 32) {
        const int r = lane >> 3;
        const int b = lane & 7;
        const int o = row0 + r;
        const float tot = total + ldsv[wave + 1][lane];
        const float Sf  = S + ldsS[wave + 1][b];
        out[(size_t)b * OUT_F + o] = scale[o] * (tot - (float)zp[o] * Sf) + bias[o];
    }
}

extern "C" void kernel_launch(void* const* d_in, const int* in_sizes, int n_in,
                              void* d_out, int out_size, void* d_ws, size_t ws_size,
                              hipStream_t stream) {
    const float* in    = (const float*)d_in[0];
    const int*   qw    = (const int*)  d_in[1];
    const int*   zp    = (const int*)  d_in[2];
    const float* scale = (const float*)d_in[3];
    const float* bias  = (const float*)d_in[4];
    float*       out   = (float*)d_out;

    const int blocks = OUT_F / 8;   // 1376 blocks: 2 groups x 2 K-halves each
    qlinear_kernel<<<blocks, 256, 0, stream>>>(in, qw, zp, scale, bias, out);
}